// Round 10
// baseline (810.356 us; speedup 1.0000x reference)
//
#include <hip/hip_runtime.h>

// Problem constants (fixed by the reference).
#define BB   32
#define TT   2048
#define FF   512
#define KK   1024
#define DD   512
#define NCMAX 512        // max active timesteps: g>=0.05 -> g*(1-g)^c >= 1e-12 needs c <= 481
#define LN_EPS 1e-5f
#define WCUT 1e-12f      // drop terms with EMA weight < 1e-12 (bounded err ~5e-11 << 5.8e-2 thr)

// ======== MEASUREMENT ROUND: internal repeat factors (idempotent reps) ========
// Inflates each kernel past the 76us ws-poison-fill floor so it shows in the
// rocprof top-5 with its own counters. True cost = dispatch_dur / REP.
#define WM_REP 32
#define BG_REP 32
#define LE_REP 64

typedef __attribute__((ext_vector_type(8))) short bf16x8;
typedef __attribute__((ext_vector_type(4))) float f32x4;

// g = clip(sigmoid(w1*cos(t1)cos(p1) + w2*cos(t2)cos(p2) + b_g), 0.05, 0.75)
__device__ __forceinline__ float compute_g(const float* th1, const float* ph1,
                                           const float* th2, const float* ph2,
                                           const float* w1, const float* w2,
                                           const float* bg) {
    float z1 = cosf(*th1) * cosf(*ph1);
    float z2 = cosf(*th2) * cosf(*ph2);
    float s  = (*w1) * z1 + (*w2) * z2 + (*bg);
    float sg = 1.0f / (1.0f + expf(-s));
    return fminf(fmaxf(sg, 0.05f), 0.75f);
}

// fp32 -> bf16 bits, round-to-nearest-even
__device__ __forceinline__ ushort f2bf(float x) {
    unsigned u = __float_as_uint(x);
    u += 0x7FFFu + ((u >> 16) & 1u);
    return (ushort)(u >> 16);
}

// ---- MFMA weight merge: CT[f][d] = sum_k Ww[d][k] * Pw[k][f] (bf16 in, fp32 acc). ----
// VERIFIED layout (R7/R8, absmax 0.0156). 64 blocks (8x8 of 64d x 64f tiles),
// 256 threads = 4 waves (2x2, each 32x32). Octet-major XOR-slot LDS layout.
// Block 0 also precomputes wj[c] = g*(1-g)^c and n_active.
__global__ __launch_bounds__(256) void weight_merge(
    const float* __restrict__ Pw, const float* __restrict__ Ww,
    float* __restrict__ CT, float* __restrict__ wj, int* __restrict__ nact,
    const float* th1, const float* ph1, const float* th2, const float* ph2,
    const float* w1p, const float* w2p, const float* bgp) {

    __shared__ __align__(16) ushort As[8 * 64 * 8];   // Ww tile, 8 KB
    __shared__ __align__(16) ushort Bs[8 * 64 * 8];   // Pw^T tile, 8 KB
    __shared__ int cnt4[4];

    const int tid = threadIdx.x;

    const int d0   = (blockIdx.x >> 3) * 64;
    const int f0   = (blockIdx.x & 7) * 64;
    const int wave = tid >> 6;
    const int lane = tid & 63;
    const int wm2  = wave >> 1;        // wave's d-half
    const int wn2  = wave & 1;         // wave's f-half
    const int lg   = lane >> 4;        // k-octet group 0..3
    const int ll   = lane & 15;        // free-index lane
    const int cw   = tid & 15;         // staging: column group
    const int rq   = tid >> 4;         // staging: row group

    for (int rep = 0; rep < WM_REP; ++rep) {
        // ---- setup prelude: only block 0 (idempotent across reps). ----
        if (blockIdx.x == 0) {
            const float g   = compute_g(th1, ph1, th2, ph2, w1p, w2p, bgp);
            const float omg = 1.0f - g;
            const float w0  = g * powf(omg, (float)tid);
            const float w1  = g * powf(omg, (float)(tid + 256));
            wj[tid]       = w0;
            wj[tid + 256] = w1;
            const unsigned long long m0 = __ballot(w0 >= WCUT);
            const unsigned long long m1 = __ballot(w1 >= WCUT);
            if ((tid & 63) == 0) cnt4[tid >> 6] = __popcll(m0) + __popcll(m1);
            __syncthreads();
            if (tid == 0) *nact = cnt4[0] + cnt4[1] + cnt4[2] + cnt4[3];
        }

        f32x4 acc00 = {0.f, 0.f, 0.f, 0.f}, acc01 = {0.f, 0.f, 0.f, 0.f};
        f32x4 acc10 = {0.f, 0.f, 0.f, 0.f}, acc11 = {0.f, 0.f, 0.f, 0.f};
        float4 wwreg[4], pwa[2], pwb[2];

#define STAGE_LOAD(kkv) do {                                                          \
        _Pragma("unroll")                                                             \
        for (int i = 0; i < 4; ++i)                                                   \
            wwreg[i] = *(const float4*)(Ww + (size_t)(d0 + rq + i * 16) * KK + (kkv) + cw * 4); \
        _Pragma("unroll")                                                             \
        for (int i = 0; i < 2; ++i) {                                                 \
            const int kr = (rq + i * 16) * 2;                                         \
            pwa[i] = *(const float4*)(Pw + (size_t)((kkv) + kr)     * FF + f0 + cw * 4); \
            pwb[i] = *(const float4*)(Pw + (size_t)((kkv) + kr + 1) * FF + f0 + cw * 4); \
        }                                                                             \
    } while (0)

        STAGE_LOAD(0);

        for (int kk = 0; kk < KK; kk += 64) {
            {   // convert + write LDS (from regs)
                const int qa = cw >> 1, ha = cw & 1;
                #pragma unroll
                for (int i = 0; i < 4; ++i) {
                    const int r = rq + i * 16;
                    ushort4 b;
                    b.x = f2bf(wwreg[i].x); b.y = f2bf(wwreg[i].y);
                    b.z = f2bf(wwreg[i].z); b.w = f2bf(wwreg[i].w);
                    *(ushort4*)&As[qa * 512 + ((r ^ (qa & 3)) << 3) + ha * 4] = b;
                }
                #pragma unroll
                for (int i = 0; i < 2; ++i) {
                    const int kr = (rq + i * 16) * 2;
                    const int q  = kr >> 3, j = kr & 7, q3 = q & 3;
                    const float fa[4] = {pwa[i].x, pwa[i].y, pwa[i].z, pwa[i].w};
                    const float fb[4] = {pwb[i].x, pwb[i].y, pwb[i].z, pwb[i].w};
                    #pragma unroll
                    for (int e = 0; e < 4; ++e) {
                        ushort2 p; p.x = f2bf(fa[e]); p.y = f2bf(fb[e]);
                        *(ushort2*)&Bs[q * 512 + (((cw * 4 + e) ^ q3) << 3) + j] = p;
                    }
                }
            }
            __syncthreads();

            if (kk + 64 < KK) STAGE_LOAD(kk + 64);   // prefetch next chunk under compute

            #pragma unroll
            for (int ks = 0; ks < 2; ++ks) {
                const int base = (ks * 4 + lg) * 512;
                const bf16x8 af0 = *(const bf16x8*)&As[base + (((wm2 * 32 +  0 + ll) ^ lg) << 3)];
                const bf16x8 af1 = *(const bf16x8*)&As[base + (((wm2 * 32 + 16 + ll) ^ lg) << 3)];
                const bf16x8 bg0 = *(const bf16x8*)&Bs[base + (((wn2 * 32 +  0 + ll) ^ lg) << 3)];
                const bf16x8 bg1 = *(const bf16x8*)&Bs[base + (((wn2 * 32 + 16 + ll) ^ lg) << 3)];
                acc00 = __builtin_amdgcn_mfma_f32_16x16x32_bf16(af0, bg0, acc00, 0, 0, 0);
                acc01 = __builtin_amdgcn_mfma_f32_16x16x32_bf16(af0, bg1, acc01, 0, 0, 0);
                acc10 = __builtin_amdgcn_mfma_f32_16x16x32_bf16(af1, bg0, acc10, 0, 0, 0);
                acc11 = __builtin_amdgcn_mfma_f32_16x16x32_bf16(af1, bg1, acc11, 0, 0, 0);
            }
            __syncthreads();
        }
#undef STAGE_LOAD

        // epilogue: CT[f][d] (D-layout HW-verified: col=lane&15 -> f, row=(lane>>4)*4+reg -> d)
        {
            const int fb = f0 + wn2 * 32 + ll;
            const int db = d0 + wm2 * 32 + lg * 4;
            *(float4*)(CT + (size_t)(fb     ) * DD + db     ) = make_float4(acc00[0], acc00[1], acc00[2], acc00[3]);
            *(float4*)(CT + (size_t)(fb + 16) * DD + db     ) = make_float4(acc01[0], acc01[1], acc01[2], acc01[3]);
            *(float4*)(CT + (size_t)(fb     ) * DD + db + 16) = make_float4(acc10[0], acc10[1], acc10[2], acc10[3]);
            *(float4*)(CT + (size_t)(fb + 16) * DD + db + 16) = make_float4(acc11[0], acc11[1], acc11[2], acc11[3]);
        }
        __syncthreads();   // LDS reuse across reps
    }
}

// ---- base_part[fq][c][b][d] = x[b][t(c)][fq-quarter] . CT[fq][d-tile]  (no bias) ----
// Grid (64, 64): bx -> fq = bx>>4 (4 f-quarters of 128), bg = (bx>>2)&3 (4 batch
// groups of 8), dt = bx&3 (4 d-tiles of 128). by = c-slot, loops c += 64 < n_active.
// 1280 active blocks at nv=20 (5 waves/SIMD); per-thread 512 FMA, 32 CT float4.
// alpha*cal_scalar is d-constant -> cancels exactly in the later LayerNorm.
__global__ __launch_bounds__(256) void base_gemm(
    const float* __restrict__ x,   const float* __restrict__ CT,
    const int* __restrict__ nact,
    float* __restrict__ base) {

    const int nv = *nact;
    if ((int)blockIdx.y >= nv) return;

    __shared__ float xs[8][128];           // 4 KB: 8 rows x f-quarter
    __shared__ float red[4][8][128];       // 16 KB: [f-slice][row][d-local]

    const int tid = threadIdx.x;
    const int fq  = blockIdx.x >> 4;
    const int bg  = (blockIdx.x >> 2) & 3;
    const int dt  = blockIdx.x & 3;

    const int rg  = tid >> 7;              // 2 row-groups of 4
    const int fs  = (tid >> 5) & 3;        // 4 f-slices of 32
    const int dl  = tid & 31;              // d-quad lane

    for (int rep = 0; rep < BG_REP; ++rep) {
        for (int c = blockIdx.y; c < nv; c += 64) {
            const int t = TT - 1 - c;

            {   // stage 8 x rows (f-quarter): 256 float4 = 1 per thread
                const int r  = tid >> 5;
                const int f4 = (tid & 31) * 4;
                *(float4*)&xs[r][f4] =
                    *(const float4*)(x + ((size_t)(bg * 8 + r) * TT + t) * FF + fq * 128 + f4);
            }
            __syncthreads();

            float4 acc[4];
            #pragma unroll
            for (int r = 0; r < 4; ++r) acc[r] = make_float4(0.f, 0.f, 0.f, 0.f);

            const float* ctp = CT + (size_t)(fq * 128 + fs * 32) * DD + dt * 128 + dl * 4;
            #pragma unroll 4
            for (int f = 0; f < 32; f += 4) {
                const float4 cv0 = *(const float4*)(ctp + (size_t)(f + 0) * DD);
                const float4 cv1 = *(const float4*)(ctp + (size_t)(f + 1) * DD);
                const float4 cv2 = *(const float4*)(ctp + (size_t)(f + 2) * DD);
                const float4 cv3 = *(const float4*)(ctp + (size_t)(f + 3) * DD);
                #pragma unroll
                for (int r = 0; r < 4; ++r) {
                    const float4 xv = *(const float4*)&xs[rg * 4 + r][fs * 32 + f];  // LDS b128
                    acc[r].x += xv.x * cv0.x + xv.y * cv1.x + xv.z * cv2.x + xv.w * cv3.x;
                    acc[r].y += xv.x * cv0.y + xv.y * cv1.y + xv.z * cv2.y + xv.w * cv3.y;
                    acc[r].z += xv.x * cv0.z + xv.y * cv1.z + xv.z * cv2.z + xv.w * cv3.z;
                    acc[r].w += xv.x * cv0.w + xv.y * cv1.w + xv.z * cv2.w + xv.w * cv3.w;
                }
            }
            #pragma unroll
            for (int r = 0; r < 4; ++r)
                *(float4*)&red[fs][rg * 4 + r][dl * 4] = acc[r];
            __syncthreads();

            {   // reduce over 4 f-slices; write raw base part
                const int r2 = tid >> 5;
                float4 s = make_float4(0.f, 0.f, 0.f, 0.f);
                #pragma unroll
                for (int q = 0; q < 4; ++q) {
                    const float4 v = *(const float4*)&red[q][r2][dl * 4];
                    s.x += v.x; s.y += v.y; s.z += v.z; s.w += v.w;
                }
                *(float4*)(base + (((size_t)fq * NCMAX + c) * BB + bg * 8 + r2) * DD + dt * 128 + dl * 4) = s;
            }
            __syncthreads();   // protect xs/red for next c / rep
        }
    }
}

// ---- LN + EMA + reduce: one block per batch. 8 waves; wave w owns c = w, w+8, ... ----
__global__ __launch_bounds__(512) void ln_ema(
    const float* __restrict__ base,
    const float* __restrict__ Wb,  const float* __restrict__ bvec,
    const float* __restrict__ lng, const float* __restrict__ lnb,
    const float* __restrict__ wj,  const int* __restrict__ nact,
    float* __restrict__ out) {

    __shared__ float hred[8][DD];   // 16 KB

    const int b   = blockIdx.x;
    const int tid = threadIdx.x;
    const int w   = tid >> 6;
    const int l   = tid & 63;
    const int nv  = *nact;

    float ga[8], be[8], bi[8];
    #pragma unroll
    for (int i = 0; i < 8; ++i) {
        ga[i] = lng[l * 8 + i];
        be[i] = lnb[l * 8 + i];
        bi[i] = Wb[l * 8 + i] + bvec[l * 8 + i];
    }

    for (int rep = 0; rep < LE_REP; ++rep) {
        float hacc[8] = {0.f, 0.f, 0.f, 0.f, 0.f, 0.f, 0.f, 0.f};

        for (int c = w; c < nv; c += 8) {
            const float wjc = wj[c];
            const float* bp = base + ((size_t)c * BB + b) * DD + l * 8;
            const size_t qstride = (size_t)NCMAX * BB * DD;
            float vv[8];
            #pragma unroll
            for (int i = 0; i < 8; ++i) vv[i] = bi[i];
            #pragma unroll
            for (int fq = 0; fq < 4; ++fq) {
                const float4 u0 = *(const float4*)(bp + fq * qstride);
                const float4 u1 = *(const float4*)(bp + fq * qstride + 4);
                vv[0] += u0.x; vv[1] += u0.y; vv[2] += u0.z; vv[3] += u0.w;
                vv[4] += u1.x; vv[5] += u1.y; vv[6] += u1.z; vv[7] += u1.w;
            }

            float S = 0.f, Q = 0.f;
            #pragma unroll
            for (int i = 0; i < 8; ++i) { S += vv[i]; Q += vv[i] * vv[i]; }
            #pragma unroll
            for (int off = 32; off >= 1; off >>= 1) {
                S += __shfl_xor(S, off);
                Q += __shfl_xor(Q, off);
            }
            const float mu   = S * (1.0f / DD);
            const float rstd = rsqrtf(Q * (1.0f / DD) - mu * mu + LN_EPS);
            #pragma unroll
            for (int i = 0; i < 8; ++i)
                hacc[i] += wjc * ((vv[i] - mu) * rstd * ga[i] + be[i]);
        }

        #pragma unroll
        for (int i = 0; i < 8; ++i) hred[w][l * 8 + i] = hacc[i];
        __syncthreads();

        {
            const int d = tid;
            float s = 0.f;
            #pragma unroll
            for (int q = 0; q < 8; ++q) s += hred[q][d];
            out[(size_t)b * DD + d] = s;
        }
        __syncthreads();   // protect hred for next rep
    }
}

extern "C" void kernel_launch(void* const* d_in, const int* in_sizes, int n_in,
                              void* d_out, int out_size, void* d_ws, size_t ws_size,
                              hipStream_t stream) {
    const float* x   = (const float*)d_in[0];
    const float* Pw  = (const float*)d_in[1];
    const float* Ww  = (const float*)d_in[2];
    const float* Wb  = (const float*)d_in[3];
    const float* bv  = (const float*)d_in[4];
    const float* lng = (const float*)d_in[5];
    const float* lnb = (const float*)d_in[6];
    // d_in[7] = alpha: unused — alpha*cal_scalar is d-constant; LayerNorm cancels it exactly.
    const float* th1 = (const float*)d_in[8];
    const float* ph1 = (const float*)d_in[9];
    const float* th2 = (const float*)d_in[10];
    const float* ph2 = (const float*)d_in[11];
    const float* w1  = (const float*)d_in[12];
    const float* w2  = (const float*)d_in[13];
    const float* bg  = (const float*)d_in[14];

    float* CT   = (float*)d_ws;                    // [F][D] = 1 MB
    float* wj   = CT + (size_t)DD * FF;            // [512] weight table
    int*   nact = (int*)(wj + 512);                // active-count
    float* base = wj + 1024;                       // [4][NCMAX][BB][DD] = 134 MB

    weight_merge<<<64, 256, 0, stream>>>(Pw, Ww, CT, wj, nact,
                                         th1, ph1, th2, ph2, w1, w2, bg);

    dim3 bgrid(64, 64);
    base_gemm<<<bgrid, 256, 0, stream>>>(x, CT, nact, base);

    ln_ema<<<BB, 512, 0, stream>>>(base, Wb, bv, lng, lnb, wj, nact, (float*)d_out);
}

// Round 11
// 36.263 us; speedup vs baseline: 22.3464x; 22.3464x over previous
//
#include <hip/hip_runtime.h>

// Problem constants (fixed by the reference).
#define BB   32
#define TT   2048
#define FF   512
#define KK   1024
#define DD   512
#define NCMAX 512        // max active timesteps: g>=0.05 -> g*(1-g)^c >= 1e-12 needs c <= 481
#define LN_EPS 1e-5f
#define WCUT 1e-12f      // drop terms with EMA weight < 1e-12 (bounded err ~5e-11 << 5.8e-2 thr)

typedef __attribute__((ext_vector_type(8))) short bf16x8;
typedef __attribute__((ext_vector_type(4))) float f32x4;

// g = clip(sigmoid(w1*cos(t1)cos(p1) + w2*cos(t2)cos(p2) + b_g), 0.05, 0.75)
__device__ __forceinline__ float compute_g(const float* th1, const float* ph1,
                                           const float* th2, const float* ph2,
                                           const float* w1, const float* w2,
                                           const float* bg) {
    float z1 = cosf(*th1) * cosf(*ph1);
    float z2 = cosf(*th2) * cosf(*ph2);
    float s  = (*w1) * z1 + (*w2) * z2 + (*bg);
    float sg = 1.0f / (1.0f + expf(-s));
    return fminf(fmaxf(sg, 0.05f), 0.75f);
}

// fp32 -> bf16 bits, round-to-nearest-even
__device__ __forceinline__ ushort f2bf(float x) {
    unsigned u = __float_as_uint(x);
    u += 0x7FFFu + ((u >> 16) & 1u);
    return (ushort)(u >> 16);
}

// ---- MFMA weight merge v2: CT[f][d] = sum_k Ww[d][k] * Pw[k][f] (bf16 in, fp32 acc) ----
// R10 PMC convicted v1: 64 blocks (75% CUs idle) + 524K bank conflicts/launch from
// sub-word LDS scatter writes. v2: 256 blocks (16x16 grid of 32x32 tiles, K=1024),
// 4 waves x 16x16 subtile. LDS cells are bf16x8 [row][slot], slot = oct ^ (row&15):
// every LDS op (write AND frag read) is a full-wave b128 at bank-balanced addresses.
// B-transpose via 8 strided L2-resident dword loads per octet (no LDS scatter).
// Operand layout (numerically VERIFIED in R7/R8, absmax 0.0156): A-frag = Ww d-row
// k-octets, B-frag = Pw^T f-row k-octets, D: col=lane&15 -> f, row=(lane>>4)*4+reg -> d.
// Block 0 also precomputes wj[c] = g*(1-g)^c and n_active.
__global__ __launch_bounds__(256) void weight_merge(
    const float* __restrict__ Pw, const float* __restrict__ Ww,
    float* __restrict__ CT, float* __restrict__ wj, int* __restrict__ nact,
    const float* th1, const float* ph1, const float* th2, const float* ph2,
    const float* w1p, const float* w2p, const float* bgp) {

    __shared__ __align__(16) ushort As[32 * 16 * 8];   // [d-row][slot] 8 KB
    __shared__ __align__(16) ushort Bs[32 * 16 * 8];   // [f-row][slot] 8 KB
    __shared__ int cnt4[4];

    const int tid = threadIdx.x;

    // ---- setup prelude: only block 0 ----
    if (blockIdx.x == 0) {
        const float g   = compute_g(th1, ph1, th2, ph2, w1p, w2p, bgp);
        const float omg = 1.0f - g;
        const float w0  = g * powf(omg, (float)tid);
        const float w1  = g * powf(omg, (float)(tid + 256));
        wj[tid]       = w0;
        wj[tid + 256] = w1;
        const unsigned long long m0 = __ballot(w0 >= WCUT);
        const unsigned long long m1 = __ballot(w1 >= WCUT);
        if ((tid & 63) == 0) cnt4[tid >> 6] = __popcll(m0) + __popcll(m1);
        __syncthreads();
        if (tid == 0) *nact = cnt4[0] + cnt4[1] + cnt4[2] + cnt4[3];
    }

    const int d0 = (blockIdx.x >> 4) * 32;
    const int f0 = (blockIdx.x & 15) * 32;

    const int wave = tid >> 6;
    const int lane = tid & 63;
    const int wm2  = wave >> 1;        // wave's d-half (16)
    const int wn2  = wave & 1;         // wave's f-half (16)
    const int lg   = lane >> 4;        // k-octet sub-group 0..3
    const int ll   = lane & 15;        // free-index lane

    const int srow = tid & 31;         // staging row (d for A, f for B)
    const int so   = tid >> 3 >> 2;    // staging octet 0..7 (handles so and so+8)

    const int arow = wm2 * 16 + ll;    // frag rows
    const int brow = wn2 * 16 + ll;

    f32x4 accA = {0.f, 0.f, 0.f, 0.f};   // ks 0,2
    f32x4 accB = {0.f, 0.f, 0.f, 0.f};   // ks 1,3

    float a0[8], a1[8], b0[8], b1[8];     // prefetch regs: A/B octets so, so+8

#define WM_LOAD(kkv) do {                                                         \
        const float* wr = Ww + (size_t)(d0 + srow) * KK + (kkv);                  \
        *(float4*)&a0[0] = *(const float4*)(wr + so * 8);                         \
        *(float4*)&a0[4] = *(const float4*)(wr + so * 8 + 4);                     \
        *(float4*)&a1[0] = *(const float4*)(wr + (so + 8) * 8);                   \
        *(float4*)&a1[4] = *(const float4*)(wr + (so + 8) * 8 + 4);               \
        const float* pr = Pw + (size_t)(kkv) * FF + f0 + srow;                    \
        _Pragma("unroll")                                                         \
        for (int j = 0; j < 8; ++j) {                                             \
            b0[j] = pr[(size_t)(so * 8 + j) * FF];                                \
            b1[j] = pr[(size_t)((so + 8) * 8 + j) * FF];                          \
        }                                                                         \
    } while (0)

#define WM_STORE() do {                                                           \
        bf16x8 va0, va1, vb0, vb1;                                                \
        _Pragma("unroll")                                                         \
        for (int e = 0; e < 8; ++e) {                                             \
            va0[e] = (short)f2bf(a0[e]); va1[e] = (short)f2bf(a1[e]);             \
            vb0[e] = (short)f2bf(b0[e]); vb1[e] = (short)f2bf(b1[e]);             \
        }                                                                         \
        const int sw = srow & 15;                                                 \
        *(bf16x8*)&As[(srow * 16 + (so ^ sw)) * 8]       = va0;                   \
        *(bf16x8*)&As[(srow * 16 + ((so + 8) ^ sw)) * 8] = va1;                   \
        *(bf16x8*)&Bs[(srow * 16 + (so ^ sw)) * 8]       = vb0;                   \
        *(bf16x8*)&Bs[(srow * 16 + ((so + 8) ^ sw)) * 8] = vb1;                   \
    } while (0)

    WM_LOAD(0);

    for (int kk = 0; kk < KK; kk += 128) {
        WM_STORE();
        __syncthreads();
        if (kk + 128 < KK) WM_LOAD(kk + 128);   // prefetch next chunk under compute

        #pragma unroll
        for (int ks = 0; ks < 4; ++ks) {
            const int oct = ks * 4 + lg;
            const bf16x8 af = *(const bf16x8*)&As[(arow * 16 + (oct ^ (arow & 15))) * 8];
            const bf16x8 bf = *(const bf16x8*)&Bs[(brow * 16 + (oct ^ (brow & 15))) * 8];
            if (ks & 1) accB = __builtin_amdgcn_mfma_f32_16x16x32_bf16(af, bf, accB, 0, 0, 0);
            else        accA = __builtin_amdgcn_mfma_f32_16x16x32_bf16(af, bf, accA, 0, 0, 0);
        }
        __syncthreads();
    }
#undef WM_LOAD
#undef WM_STORE

    // epilogue: CT[f][d] (D-layout HW-verified: col=lane&15 -> f, row=(lane>>4)*4+reg -> d)
    {
        const f32x4 acc = accA + accB;
        const int fb = f0 + wn2 * 16 + ll;
        const int db = d0 + wm2 * 16 + lg * 4;
        *(float4*)(CT + (size_t)fb * DD + db) = make_float4(acc[0], acc[1], acc[2], acc[3]);
    }
}

// ---- base_part[fq][c][b][d] = x[b][t(c)][fq-quarter] . CT[fq][d-tile]  (no bias) ----
// Grid (64, 64): bx -> fq = bx>>4 (4 f-quarters of 128), bg = (bx>>2)&3 (4 batch
// groups of 8), dt = bx&3 (4 d-tiles of 128). by = c-slot, loops c += 64 < n_active.
// alpha*cal_scalar is d-constant -> cancels exactly in the later LayerNorm.
__global__ __launch_bounds__(256) void base_gemm(
    const float* __restrict__ x,   const float* __restrict__ CT,
    const int* __restrict__ nact,
    float* __restrict__ base) {

    const int nv = *nact;
    if ((int)blockIdx.y >= nv) return;

    __shared__ float xs[8][128];           // 4 KB: 8 rows x f-quarter
    __shared__ float red[4][8][128];       // 16 KB: [f-slice][row][d-local]

    const int tid = threadIdx.x;
    const int fq  = blockIdx.x >> 4;
    const int bg  = (blockIdx.x >> 2) & 3;
    const int dt  = blockIdx.x & 3;

    const int rg  = tid >> 7;              // 2 row-groups of 4
    const int fs  = (tid >> 5) & 3;        // 4 f-slices of 32
    const int dl  = tid & 31;              // d-quad lane

    for (int c = blockIdx.y; c < nv; c += 64) {
        const int t = TT - 1 - c;

        {   // stage 8 x rows (f-quarter): 256 float4 = 1 per thread
            const int r  = tid >> 5;
            const int f4 = (tid & 31) * 4;
            *(float4*)&xs[r][f4] =
                *(const float4*)(x + ((size_t)(bg * 8 + r) * TT + t) * FF + fq * 128 + f4);
        }
        __syncthreads();

        float4 acc[4];
        #pragma unroll
        for (int r = 0; r < 4; ++r) acc[r] = make_float4(0.f, 0.f, 0.f, 0.f);

        const float* ctp = CT + (size_t)(fq * 128 + fs * 32) * DD + dt * 128 + dl * 4;
        #pragma unroll 4
        for (int f = 0; f < 32; f += 4) {
            const float4 cv0 = *(const float4*)(ctp + (size_t)(f + 0) * DD);
            const float4 cv1 = *(const float4*)(ctp + (size_t)(f + 1) * DD);
            const float4 cv2 = *(const float4*)(ctp + (size_t)(f + 2) * DD);
            const float4 cv3 = *(const float4*)(ctp + (size_t)(f + 3) * DD);
            #pragma unroll
            for (int r = 0; r < 4; ++r) {
                const float4 xv = *(const float4*)&xs[rg * 4 + r][fs * 32 + f];  // LDS b128
                acc[r].x += xv.x * cv0.x + xv.y * cv1.x + xv.z * cv2.x + xv.w * cv3.x;
                acc[r].y += xv.x * cv0.y + xv.y * cv1.y + xv.z * cv2.y + xv.w * cv3.y;
                acc[r].z += xv.x * cv0.z + xv.y * cv1.z + xv.z * cv2.z + xv.w * cv3.z;
                acc[r].w += xv.x * cv0.w + xv.y * cv1.w + xv.z * cv2.w + xv.w * cv3.w;
            }
        }
        #pragma unroll
        for (int r = 0; r < 4; ++r)
            *(float4*)&red[fs][rg * 4 + r][dl * 4] = acc[r];
        __syncthreads();

        {   // reduce over 4 f-slices; write raw base part
            const int r2 = tid >> 5;
            float4 s = make_float4(0.f, 0.f, 0.f, 0.f);
            #pragma unroll
            for (int q = 0; q < 4; ++q) {
                const float4 v = *(const float4*)&red[q][r2][dl * 4];
                s.x += v.x; s.y += v.y; s.z += v.z; s.w += v.w;
            }
            *(float4*)(base + (((size_t)fq * NCMAX + c) * BB + bg * 8 + r2) * DD + dt * 128 + dl * 4) = s;
        }
        __syncthreads();   // protect xs/red for next c
    }
}

// ---- LN + EMA + reduce: one block per batch. 8 waves; wave w owns c = w, w+8, ... ----
__global__ __launch_bounds__(512) void ln_ema(
    const float* __restrict__ base,
    const float* __restrict__ Wb,  const float* __restrict__ bvec,
    const float* __restrict__ lng, const float* __restrict__ lnb,
    const float* __restrict__ wj,  const int* __restrict__ nact,
    float* __restrict__ out) {

    __shared__ float hred[8][DD];   // 16 KB

    const int b   = blockIdx.x;
    const int tid = threadIdx.x;
    const int w   = tid >> 6;
    const int l   = tid & 63;
    const int nv  = *nact;

    float ga[8], be[8], bi[8];
    #pragma unroll
    for (int i = 0; i < 8; ++i) {
        ga[i] = lng[l * 8 + i];
        be[i] = lnb[l * 8 + i];
        bi[i] = Wb[l * 8 + i] + bvec[l * 8 + i];
    }

    float hacc[8] = {0.f, 0.f, 0.f, 0.f, 0.f, 0.f, 0.f, 0.f};

    for (int c = w; c < nv; c += 8) {
        const float wjc = wj[c];
        const float* bp = base + ((size_t)c * BB + b) * DD + l * 8;
        const size_t qstride = (size_t)NCMAX * BB * DD;
        float vv[8];
        #pragma unroll
        for (int i = 0; i < 8; ++i) vv[i] = bi[i];
        #pragma unroll
        for (int fq = 0; fq < 4; ++fq) {
            const float4 u0 = *(const float4*)(bp + fq * qstride);
            const float4 u1 = *(const float4*)(bp + fq * qstride + 4);
            vv[0] += u0.x; vv[1] += u0.y; vv[2] += u0.z; vv[3] += u0.w;
            vv[4] += u1.x; vv[5] += u1.y; vv[6] += u1.z; vv[7] += u1.w;
        }

        float S = 0.f, Q = 0.f;
        #pragma unroll
        for (int i = 0; i < 8; ++i) { S += vv[i]; Q += vv[i] * vv[i]; }
        #pragma unroll
        for (int off = 32; off >= 1; off >>= 1) {
            S += __shfl_xor(S, off);
            Q += __shfl_xor(Q, off);
        }
        const float mu   = S * (1.0f / DD);
        const float rstd = rsqrtf(Q * (1.0f / DD) - mu * mu + LN_EPS);
        #pragma unroll
        for (int i = 0; i < 8; ++i)
            hacc[i] += wjc * ((vv[i] - mu) * rstd * ga[i] + be[i]);
    }

    #pragma unroll
    for (int i = 0; i < 8; ++i) hred[w][l * 8 + i] = hacc[i];
    __syncthreads();

    {
        const int d = tid;
        float s = 0.f;
        #pragma unroll
        for (int q = 0; q < 8; ++q) s += hred[q][d];
        out[(size_t)b * DD + d] = s;
    }
}

extern "C" void kernel_launch(void* const* d_in, const int* in_sizes, int n_in,
                              void* d_out, int out_size, void* d_ws, size_t ws_size,
                              hipStream_t stream) {
    const float* x   = (const float*)d_in[0];
    const float* Pw  = (const float*)d_in[1];
    const float* Ww  = (const float*)d_in[2];
    const float* Wb  = (const float*)d_in[3];
    const float* bv  = (const float*)d_in[4];
    const float* lng = (const float*)d_in[5];
    const float* lnb = (const float*)d_in[6];
    // d_in[7] = alpha: unused — alpha*cal_scalar is d-constant; LayerNorm cancels it exactly.
    const float* th1 = (const float*)d_in[8];
    const float* ph1 = (const float*)d_in[9];
    const float* th2 = (const float*)d_in[10];
    const float* ph2 = (const float*)d_in[11];
    const float* w1  = (const float*)d_in[12];
    const float* w2  = (const float*)d_in[13];
    const float* bg  = (const float*)d_in[14];

    float* CT   = (float*)d_ws;                    // [F][D] = 1 MB
    float* wj   = CT + (size_t)DD * FF;            // [512] weight table
    int*   nact = (int*)(wj + 512);                // active-count
    float* base = wj + 1024;                       // [4][NCMAX][BB][DD] = 134 MB

    weight_merge<<<256, 256, 0, stream>>>(Pw, Ww, CT, wj, nact,
                                          th1, ph1, th2, ph2, w1, w2, bg);

    dim3 bgrid(64, 64);
    base_gemm<<<bgrid, 256, 0, stream>>>(x, CT, nact, base);

    ln_ema<<<BB, 512, 0, stream>>>(base, Wb, bv, lng, lnb, wj, nact, (float*)d_out);
}

// Round 12
// 35.577 us; speedup vs baseline: 22.7773x; 1.0193x over previous
//
#include <hip/hip_runtime.h>

// Problem constants (fixed by the reference).
#define BB   32
#define TT   2048
#define FF   512
#define KK   1024
#define DD   512
#define NCMAX 512        // max active timesteps: g>=0.05 -> g*(1-g)^c >= 1e-12 needs c <= 481
#define LN_EPS 1e-5f
#define WCUT 1e-12f      // drop terms with EMA weight < 1e-12 (bounded err ~5e-11 << 5.8e-2 thr)

typedef __attribute__((ext_vector_type(8))) short bf16x8;
typedef __attribute__((ext_vector_type(4))) float f32x4;

// g = clip(sigmoid(w1*cos(t1)cos(p1) + w2*cos(t2)cos(p2) + b_g), 0.05, 0.75)
__device__ __forceinline__ float compute_g(const float* th1, const float* ph1,
                                           const float* th2, const float* ph2,
                                           const float* w1, const float* w2,
                                           const float* bg) {
    float z1 = cosf(*th1) * cosf(*ph1);
    float z2 = cosf(*th2) * cosf(*ph2);
    float s  = (*w1) * z1 + (*w2) * z2 + (*bg);
    float sg = 1.0f / (1.0f + expf(-s));
    return fminf(fmaxf(sg, 0.05f), 0.75f);
}

// fp32 -> bf16 bits, round-to-nearest-even
__device__ __forceinline__ ushort f2bf(float x) {
    unsigned u = __float_as_uint(x);
    u += 0x7FFFu + ((u >> 16) & 1u);
    return (ushort)(u >> 16);
}

// ---- MFMA weight merge: Cbf[d][f] = bf16( sum_k Ww[d][k] * Pw[k][f] ) ----
// Structure identical to R11 (bank-conflict-free, 256 blocks, verified absmax
// 0.0156); only the epilogue changed: emit bf16 C row-major [d][f] — exactly the
// B-operand layout base_mfma needs (lane: d-row = ll, f-octet = lg).
// Block 0 also precomputes wj[c] = g*(1-g)^c and n_active.
__global__ __launch_bounds__(256) void weight_merge(
    const float* __restrict__ Pw, const float* __restrict__ Ww,
    ushort* __restrict__ Cbf, float* __restrict__ wj, int* __restrict__ nact,
    const float* th1, const float* ph1, const float* th2, const float* ph2,
    const float* w1p, const float* w2p, const float* bgp) {

    __shared__ __align__(16) ushort As[32 * 16 * 8];   // [d-row][slot] 8 KB
    __shared__ __align__(16) ushort Bs[32 * 16 * 8];   // [f-row][slot] 8 KB
    __shared__ int cnt4[4];

    const int tid = threadIdx.x;

    // ---- setup prelude: only block 0 ----
    if (blockIdx.x == 0) {
        const float g   = compute_g(th1, ph1, th2, ph2, w1p, w2p, bgp);
        const float omg = 1.0f - g;
        const float w0  = g * powf(omg, (float)tid);
        const float w1  = g * powf(omg, (float)(tid + 256));
        wj[tid]       = w0;
        wj[tid + 256] = w1;
        const unsigned long long m0 = __ballot(w0 >= WCUT);
        const unsigned long long m1 = __ballot(w1 >= WCUT);
        if ((tid & 63) == 0) cnt4[tid >> 6] = __popcll(m0) + __popcll(m1);
        __syncthreads();
        if (tid == 0) *nact = cnt4[0] + cnt4[1] + cnt4[2] + cnt4[3];
    }

    const int d0 = (blockIdx.x >> 4) * 32;
    const int f0 = (blockIdx.x & 15) * 32;

    const int wave = tid >> 6;
    const int lane = tid & 63;
    const int wm2  = wave >> 1;        // wave's d-half (16)
    const int wn2  = wave & 1;         // wave's f-half (16)
    const int lg   = lane >> 4;        // k-octet sub-group 0..3
    const int ll   = lane & 15;        // free-index lane

    const int srow = tid & 31;         // staging row (d for A, f for B)
    const int so   = tid >> 5;         // staging octet 0..7 (handles so and so+8)

    const int arow = wm2 * 16 + ll;    // frag rows
    const int brow = wn2 * 16 + ll;

    f32x4 accA = {0.f, 0.f, 0.f, 0.f};   // ks 0,2
    f32x4 accB = {0.f, 0.f, 0.f, 0.f};   // ks 1,3

    float a0[8], a1[8], b0[8], b1[8];     // prefetch regs: A/B octets so, so+8

#define WM_LOAD(kkv) do {                                                         \
        const float* wr = Ww + (size_t)(d0 + srow) * KK + (kkv);                  \
        *(float4*)&a0[0] = *(const float4*)(wr + so * 8);                         \
        *(float4*)&a0[4] = *(const float4*)(wr + so * 8 + 4);                     \
        *(float4*)&a1[0] = *(const float4*)(wr + (so + 8) * 8);                   \
        *(float4*)&a1[4] = *(const float4*)(wr + (so + 8) * 8 + 4);               \
        const float* pr = Pw + (size_t)(kkv) * FF + f0 + srow;                    \
        _Pragma("unroll")                                                         \
        for (int j = 0; j < 8; ++j) {                                             \
            b0[j] = pr[(size_t)(so * 8 + j) * FF];                                \
            b1[j] = pr[(size_t)((so + 8) * 8 + j) * FF];                          \
        }                                                                         \
    } while (0)

#define WM_STORE() do {                                                           \
        bf16x8 va0, va1, vb0, vb1;                                                \
        _Pragma("unroll")                                                         \
        for (int e = 0; e < 8; ++e) {                                             \
            va0[e] = (short)f2bf(a0[e]); va1[e] = (short)f2bf(a1[e]);             \
            vb0[e] = (short)f2bf(b0[e]); vb1[e] = (short)f2bf(b1[e]);             \
        }                                                                         \
        const int sw = srow & 15;                                                 \
        *(bf16x8*)&As[(srow * 16 + (so ^ sw)) * 8]       = va0;                   \
        *(bf16x8*)&As[(srow * 16 + ((so + 8) ^ sw)) * 8] = va1;                   \
        *(bf16x8*)&Bs[(srow * 16 + (so ^ sw)) * 8]       = vb0;                   \
        *(bf16x8*)&Bs[(srow * 16 + ((so + 8) ^ sw)) * 8] = vb1;                   \
    } while (0)

    WM_LOAD(0);

    for (int kk = 0; kk < KK; kk += 128) {
        WM_STORE();
        __syncthreads();
        if (kk + 128 < KK) WM_LOAD(kk + 128);   // prefetch next chunk under compute

        #pragma unroll
        for (int ks = 0; ks < 4; ++ks) {
            const int oct = ks * 4 + lg;
            const bf16x8 af = *(const bf16x8*)&As[(arow * 16 + (oct ^ (arow & 15))) * 8];
            const bf16x8 bf = *(const bf16x8*)&Bs[(brow * 16 + (oct ^ (brow & 15))) * 8];
            if (ks & 1) accB = __builtin_amdgcn_mfma_f32_16x16x32_bf16(af, bf, accB, 0, 0, 0);
            else        accA = __builtin_amdgcn_mfma_f32_16x16x32_bf16(af, bf, accA, 0, 0, 0);
        }
        __syncthreads();
    }
#undef WM_LOAD
#undef WM_STORE

    // epilogue: Cbf[d][f] bf16 (D-layout HW-verified: col=lane&15 -> f, row -> d)
    {
        const f32x4 acc = accA + accB;
        const int fb = f0 + wn2 * 16 + ll;
        const int db = d0 + wm2 * 16 + lg * 4;
        #pragma unroll
        for (int j = 0; j < 4; ++j)
            Cbf[(size_t)(db + j) * FF + fb] = f2bf(acc[j]);
    }
}

// ---- base_mfma: base[c][b][d] = x[b][t(c)] . C[d][:]  via bf16 MFMA ----
// Grid (64, 2): cslot (loops c += 64 < n_active), rh = batch half (16 rows).
// 512 threads = 8 waves; wave w owns d in [w*64, w*64+64) as 4 16x16 tiles.
// A = x rows staged to LDS bf16 with octet-XOR swizzle (2-way bank = free);
// B = Cbf rows read from L2. Same verified operand convention as weight_merge.
// alpha*cal_scalar is d-constant -> cancels exactly in the later LayerNorm.
__global__ __launch_bounds__(512) void base_mfma(
    const float* __restrict__ x, const ushort* __restrict__ Cbf,
    const int* __restrict__ nact,
    float* __restrict__ base) {

    const int nv = *nact;
    const int cslot = blockIdx.x;
    if (cslot >= nv) return;
    const int rh = blockIdx.y;

    __shared__ __align__(16) ushort xls[16 * 64 * 8];   // 16 rows x 64 f-octets, 16 KB

    const int tid  = threadIdx.x;
    const int w    = tid >> 6;
    const int lane = tid & 63;
    const int ll   = lane & 15;
    const int lg   = lane >> 4;

    for (int c = cslot; c < nv; c += 64) {
        const int t = TT - 1 - c;

        // stage 16 x rows -> bf16 LDS, octet-swizzled (o ^ (r&7)); coalesced loads
        #pragma unroll
        for (int i2 = 0; i2 < 2; ++i2) {
            const int i = tid + i2 * 512;
            const int r = i >> 6, o = i & 63;
            const float* src = x + ((size_t)(rh * 16 + r) * TT + t) * FF + o * 8;
            const float4 u0 = *(const float4*)src;
            const float4 u1 = *(const float4*)(src + 4);
            bf16x8 v;
            v[0] = (short)f2bf(u0.x); v[1] = (short)f2bf(u0.y);
            v[2] = (short)f2bf(u0.z); v[3] = (short)f2bf(u0.w);
            v[4] = (short)f2bf(u1.x); v[5] = (short)f2bf(u1.y);
            v[6] = (short)f2bf(u1.z); v[7] = (short)f2bf(u1.w);
            *(bf16x8*)&xls[(r * 64 + (o ^ (r & 7))) * 8] = v;
        }
        __syncthreads();

        f32x4 acc0 = {0.f,0.f,0.f,0.f}, acc1 = {0.f,0.f,0.f,0.f};
        f32x4 acc2 = {0.f,0.f,0.f,0.f}, acc3 = {0.f,0.f,0.f,0.f};

        #pragma unroll 4
        for (int ks = 0; ks < 16; ++ks) {
            const int oct = ks * 4 + lg;
            const bf16x8 af = *(const bf16x8*)&xls[(ll * 64 + (oct ^ (ll & 7))) * 8];
            const ushort* cp = Cbf + (size_t)(w * 64 + ll) * FF + ks * 32 + lg * 8;
            const bf16x8 bf0 = *(const bf16x8*)(cp);
            const bf16x8 bf1 = *(const bf16x8*)(cp + 16 * FF);
            const bf16x8 bf2 = *(const bf16x8*)(cp + 32 * FF);
            const bf16x8 bf3 = *(const bf16x8*)(cp + 48 * FF);
            acc0 = __builtin_amdgcn_mfma_f32_16x16x32_bf16(af, bf0, acc0, 0, 0, 0);
            acc1 = __builtin_amdgcn_mfma_f32_16x16x32_bf16(af, bf1, acc1, 0, 0, 0);
            acc2 = __builtin_amdgcn_mfma_f32_16x16x32_bf16(af, bf2, acc2, 0, 0, 0);
            acc3 = __builtin_amdgcn_mfma_f32_16x16x32_bf16(af, bf3, acc3, 0, 0, 0);
        }

        // D-layout: col = ll -> d, row = lg*4+reg -> local batch row
        {
            float* bp = base + ((size_t)c * BB + rh * 16 + lg * 4) * DD;
            #pragma unroll
            for (int reg = 0; reg < 4; ++reg) {
                float* row = bp + (size_t)reg * DD + ll;
                row[w * 64 +  0] = acc0[reg];
                row[w * 64 + 16] = acc1[reg];
                row[w * 64 + 32] = acc2[reg];
                row[w * 64 + 48] = acc3[reg];
            }
        }
        __syncthreads();   // protect xls for next c
    }
}

// ---- LN + EMA + reduce: one block per batch. 8 waves; wave w owns c = w, w+8, ... ----
__global__ __launch_bounds__(512) void ln_ema(
    const float* __restrict__ base,
    const float* __restrict__ Wb,  const float* __restrict__ bvec,
    const float* __restrict__ lng, const float* __restrict__ lnb,
    const float* __restrict__ wj,  const int* __restrict__ nact,
    float* __restrict__ out) {

    __shared__ float hred[8][DD];   // 16 KB

    const int b   = blockIdx.x;
    const int tid = threadIdx.x;
    const int w   = tid >> 6;
    const int l   = tid & 63;
    const int nv  = *nact;

    float ga[8], be[8], bi[8];
    #pragma unroll
    for (int i = 0; i < 8; ++i) {
        ga[i] = lng[l * 8 + i];
        be[i] = lnb[l * 8 + i];
        bi[i] = Wb[l * 8 + i] + bvec[l * 8 + i];
    }

    float hacc[8] = {0.f, 0.f, 0.f, 0.f, 0.f, 0.f, 0.f, 0.f};

    for (int c = w; c < nv; c += 8) {
        const float wjc = wj[c];
        const float* bp = base + ((size_t)c * BB + b) * DD + l * 8;
        const float4 u0 = *(const float4*)(bp);
        const float4 u1 = *(const float4*)(bp + 4);
        float vv[8];
        vv[0] = u0.x + bi[0]; vv[1] = u0.y + bi[1];
        vv[2] = u0.z + bi[2]; vv[3] = u0.w + bi[3];
        vv[4] = u1.x + bi[4]; vv[5] = u1.y + bi[5];
        vv[6] = u1.z + bi[6]; vv[7] = u1.w + bi[7];

        float S = 0.f, Q = 0.f;
        #pragma unroll
        for (int i = 0; i < 8; ++i) { S += vv[i]; Q += vv[i] * vv[i]; }
        #pragma unroll
        for (int off = 32; off >= 1; off >>= 1) {
            S += __shfl_xor(S, off);
            Q += __shfl_xor(Q, off);
        }
        const float mu   = S * (1.0f / DD);
        const float rstd = rsqrtf(Q * (1.0f / DD) - mu * mu + LN_EPS);
        #pragma unroll
        for (int i = 0; i < 8; ++i)
            hacc[i] += wjc * ((vv[i] - mu) * rstd * ga[i] + be[i]);
    }

    #pragma unroll
    for (int i = 0; i < 8; ++i) hred[w][l * 8 + i] = hacc[i];
    __syncthreads();

    {
        const int d = tid;
        float s = 0.f;
        #pragma unroll
        for (int q = 0; q < 8; ++q) s += hred[q][d];
        out[(size_t)b * DD + d] = s;
    }
}

extern "C" void kernel_launch(void* const* d_in, const int* in_sizes, int n_in,
                              void* d_out, int out_size, void* d_ws, size_t ws_size,
                              hipStream_t stream) {
    const float* x   = (const float*)d_in[0];
    const float* Pw  = (const float*)d_in[1];
    const float* Ww  = (const float*)d_in[2];
    const float* Wb  = (const float*)d_in[3];
    const float* bv  = (const float*)d_in[4];
    const float* lng = (const float*)d_in[5];
    const float* lnb = (const float*)d_in[6];
    // d_in[7] = alpha: unused — alpha*cal_scalar is d-constant; LayerNorm cancels it exactly.
    const float* th1 = (const float*)d_in[8];
    const float* ph1 = (const float*)d_in[9];
    const float* th2 = (const float*)d_in[10];
    const float* ph2 = (const float*)d_in[11];
    const float* w1  = (const float*)d_in[12];
    const float* w2  = (const float*)d_in[13];
    const float* bg  = (const float*)d_in[14];

    ushort* Cbf = (ushort*)d_ws;                           // [D][F] bf16 = 512 KB
    float*  wj  = (float*)((char*)d_ws + (1 << 19));       // [512] weight table
    int*    nact = (int*)(wj + 512);                       // active-count
    float*  base = (float*)((char*)d_ws + (1 << 19) + 4096);  // [NCMAX][BB][DD] = 33.5 MB

    weight_merge<<<256, 256, 0, stream>>>(Pw, Ww, Cbf, wj, nact,
                                          th1, ph1, th2, ph2, w1, w2, bg);

    dim3 bgrid(64, 2);
    base_mfma<<<bgrid, 512, 0, stream>>>(x, Cbf, nact, base);

    ln_ema<<<BB, 512, 0, stream>>>(base, Wb, bv, lng, lnb, wj, nact, (float*)d_out);
}

// Round 13
// 33.480 us; speedup vs baseline: 24.2045x; 1.0627x over previous
//
#include <hip/hip_runtime.h>

// Problem constants (fixed by the reference).
#define BB   32
#define TT   2048
#define FF   512
#define KK   1024
#define DD   512
#define NCMAX 512        // max active timesteps: g>=0.05 -> g*(1-g)^c >= 1e-12 needs c <= 481
#define LN_EPS 1e-5f
#define WCUT 1e-12f      // drop terms with EMA weight < 1e-12 (bounded err ~5e-11 << 5.8e-2 thr)

typedef __attribute__((ext_vector_type(8))) short bf16x8;
typedef __attribute__((ext_vector_type(4))) float f32x4;

// g = clip(sigmoid(w1*cos(t1)cos(p1) + w2*cos(t2)cos(p2) + b_g), 0.05, 0.75)
__device__ __forceinline__ float compute_g(const float* th1, const float* ph1,
                                           const float* th2, const float* ph2,
                                           const float* w1, const float* w2,
                                           const float* bg) {
    float z1 = cosf(*th1) * cosf(*ph1);
    float z2 = cosf(*th2) * cosf(*ph2);
    float s  = (*w1) * z1 + (*w2) * z2 + (*bg);
    float sg = 1.0f / (1.0f + expf(-s));
    return fminf(fmaxf(sg, 0.05f), 0.75f);
}

// fp32 -> bf16 bits, round-to-nearest-even
__device__ __forceinline__ ushort f2bf(float x) {
    unsigned u = __float_as_uint(x);
    u += 0x7FFFu + ((u >> 16) & 1u);
    return (ushort)(u >> 16);
}

// ---- MFMA weight merge: Cbf[d][f] = bf16( sum_k Ww[d][k] * Pw[k][f] ) ----
// Verified structure (R11/R12): 256 blocks (16x16 of 32x32 tiles), bank-conflict-free
// octet-XOR LDS, bf16 row-major [d][f] epilogue (= base_ln's B-operand layout).
// Block 0 precomputes wj[c] = g*(1-g)^c and n_active. Block 1 zeroes d_out
// (required every launch: base_ln accumulates into it with atomics).
__global__ __launch_bounds__(256) void weight_merge(
    const float* __restrict__ Pw, const float* __restrict__ Ww,
    ushort* __restrict__ Cbf, float* __restrict__ wj, int* __restrict__ nact,
    float* __restrict__ out,
    const float* th1, const float* ph1, const float* th2, const float* ph2,
    const float* w1p, const float* w2p, const float* bgp) {

    __shared__ __align__(16) ushort As[32 * 16 * 8];   // [d-row][slot] 8 KB
    __shared__ __align__(16) ushort Bs[32 * 16 * 8];   // [f-row][slot] 8 KB
    __shared__ int cnt4[4];

    const int tid = threadIdx.x;

    // ---- preludes ----
    if (blockIdx.x == 0) {
        const float g   = compute_g(th1, ph1, th2, ph2, w1p, w2p, bgp);
        const float omg = 1.0f - g;
        const float w0  = g * powf(omg, (float)tid);
        const float w1  = g * powf(omg, (float)(tid + 256));
        wj[tid]       = w0;
        wj[tid + 256] = w1;
        const unsigned long long m0 = __ballot(w0 >= WCUT);
        const unsigned long long m1 = __ballot(w1 >= WCUT);
        if ((tid & 63) == 0) cnt4[tid >> 6] = __popcll(m0) + __popcll(m1);
        __syncthreads();
        if (tid == 0) *nact = cnt4[0] + cnt4[1] + cnt4[2] + cnt4[3];
    } else if (blockIdx.x == 1) {
        // zero d_out (BB*DD floats = 64 KB) for this launch's atomic accumulation
        float4 z = make_float4(0.f, 0.f, 0.f, 0.f);
        #pragma unroll
        for (int i = 0; i < BB * DD / 4 / 256; ++i)
            *(float4*)(out + (size_t)(i * 256 + tid) * 4) = z;
    }

    const int d0 = (blockIdx.x >> 4) * 32;
    const int f0 = (blockIdx.x & 15) * 32;

    const int wave = tid >> 6;
    const int lane = tid & 63;
    const int wm2  = wave >> 1;        // wave's d-half (16)
    const int wn2  = wave & 1;         // wave's f-half (16)
    const int lg   = lane >> 4;        // k-octet sub-group 0..3
    const int ll   = lane & 15;        // free-index lane

    const int srow = tid & 31;         // staging row (d for A, f for B)
    const int so   = tid >> 5;         // staging octet 0..7 (handles so and so+8)

    const int arow = wm2 * 16 + ll;    // frag rows
    const int brow = wn2 * 16 + ll;

    f32x4 accA = {0.f, 0.f, 0.f, 0.f};   // ks 0,2
    f32x4 accB = {0.f, 0.f, 0.f, 0.f};   // ks 1,3

    float a0[8], a1[8], b0[8], b1[8];     // prefetch regs: A/B octets so, so+8

#define WM_LOAD(kkv) do {                                                         \
        const float* wr = Ww + (size_t)(d0 + srow) * KK + (kkv);                  \
        *(float4*)&a0[0] = *(const float4*)(wr + so * 8);                         \
        *(float4*)&a0[4] = *(const float4*)(wr + so * 8 + 4);                     \
        *(float4*)&a1[0] = *(const float4*)(wr + (so + 8) * 8);                   \
        *(float4*)&a1[4] = *(const float4*)(wr + (so + 8) * 8 + 4);               \
        const float* pr = Pw + (size_t)(kkv) * FF + f0 + srow;                    \
        _Pragma("unroll")                                                         \
        for (int j = 0; j < 8; ++j) {                                             \
            b0[j] = pr[(size_t)(so * 8 + j) * FF];                                \
            b1[j] = pr[(size_t)((so + 8) * 8 + j) * FF];                          \
        }                                                                         \
    } while (0)

#define WM_STORE() do {                                                           \
        bf16x8 va0, va1, vb0, vb1;                                                \
        _Pragma("unroll")                                                         \
        for (int e = 0; e < 8; ++e) {                                             \
            va0[e] = (short)f2bf(a0[e]); va1[e] = (short)f2bf(a1[e]);             \
            vb0[e] = (short)f2bf(b0[e]); vb1[e] = (short)f2bf(b1[e]);             \
        }                                                                         \
        const int sw = srow & 15;                                                 \
        *(bf16x8*)&As[(srow * 16 + (so ^ sw)) * 8]       = va0;                   \
        *(bf16x8*)&As[(srow * 16 + ((so + 8) ^ sw)) * 8] = va1;                   \
        *(bf16x8*)&Bs[(srow * 16 + (so ^ sw)) * 8]       = vb0;                   \
        *(bf16x8*)&Bs[(srow * 16 + ((so + 8) ^ sw)) * 8] = vb1;                   \
    } while (0)

    WM_LOAD(0);

    for (int kk = 0; kk < KK; kk += 128) {
        WM_STORE();
        __syncthreads();
        if (kk + 128 < KK) WM_LOAD(kk + 128);   // prefetch next chunk under compute

        #pragma unroll
        for (int ks = 0; ks < 4; ++ks) {
            const int oct = ks * 4 + lg;
            const bf16x8 af = *(const bf16x8*)&As[(arow * 16 + (oct ^ (arow & 15))) * 8];
            const bf16x8 bf = *(const bf16x8*)&Bs[(brow * 16 + (oct ^ (brow & 15))) * 8];
            if (ks & 1) accB = __builtin_amdgcn_mfma_f32_16x16x32_bf16(af, bf, accB, 0, 0, 0);
            else        accA = __builtin_amdgcn_mfma_f32_16x16x32_bf16(af, bf, accA, 0, 0, 0);
        }
        __syncthreads();
    }
#undef WM_LOAD
#undef WM_STORE

    // epilogue: Cbf[d][f] bf16 (D-layout HW-verified: col=lane&15 -> f, row -> d)
    {
        const f32x4 acc = accA + accB;
        const int fb = f0 + wn2 * 16 + ll;
        const int db = d0 + wm2 * 16 + lg * 4;
        #pragma unroll
        for (int j = 0; j < 4; ++j)
            Cbf[(size_t)(db + j) * FF + fb] = f2bf(acc[j]);
    }
}

// ---- base_ln: base = x . C^T (bf16 MFMA) -> +bias -> LayerNorm -> EMA-weight ->
//      atomicAdd into out. Grid (64, 2): cslot loops c += 64 < n_active; rh = batch
//      half (16 rows). 512 threads = 8 waves; wave w owns d in [w*64, w*64+64).
//      Per thread: acc_j[reg] = base[row = lg*4+reg][d = w*64+j*16+ll].
//      Row-sum = in-wave 16-lane shuffle (ll) + 8-wave LDS table (w) + j in-reg.
//      alpha*cal_scalar is d-constant -> cancels exactly in LN -> never computed.
__global__ __launch_bounds__(512) void base_ln(
    const float* __restrict__ x, const ushort* __restrict__ Cbf,
    const float* __restrict__ Wb, const float* __restrict__ bvec,
    const float* __restrict__ lng, const float* __restrict__ lnb,
    const float* __restrict__ wj, const int* __restrict__ nact,
    float* __restrict__ out) {

    const int nv = *nact;
    const int cslot = blockIdx.x;
    if (cslot >= nv) return;
    const int rh = blockIdx.y;

    __shared__ __align__(16) ushort xls[16 * 64 * 8];   // 16 KB
    __shared__ float redw[8][4][4][2];                  // [wave][lg][reg][S,Q] 1 KB

    const int tid  = threadIdx.x;
    const int w    = tid >> 6;
    const int lane = tid & 63;
    const int ll   = lane & 15;
    const int lg   = lane >> 4;

    // per-thread d-params: d_j = w*64 + j*16 + ll
    float bias[4], gam[4], bet[4];
    #pragma unroll
    for (int j = 0; j < 4; ++j) {
        const int d = w * 64 + j * 16 + ll;
        bias[j] = Wb[d] + bvec[d];
        gam[j]  = lng[d];
        bet[j]  = lnb[d];
    }

    float hacc[4][4];   // [j][reg]
    #pragma unroll
    for (int j = 0; j < 4; ++j)
        #pragma unroll
        for (int r = 0; r < 4; ++r) hacc[j][r] = 0.f;

    for (int c = cslot; c < nv; c += 64) {
        const int t = TT - 1 - c;

        // stage 16 x rows -> bf16 LDS, octet-swizzled (o ^ (r&7)); coalesced loads
        #pragma unroll
        for (int i2 = 0; i2 < 2; ++i2) {
            const int i = tid + i2 * 512;
            const int r = i >> 6, o = i & 63;
            const float* src = x + ((size_t)(rh * 16 + r) * TT + t) * FF + o * 8;
            const float4 u0 = *(const float4*)src;
            const float4 u1 = *(const float4*)(src + 4);
            bf16x8 v;
            v[0] = (short)f2bf(u0.x); v[1] = (short)f2bf(u0.y);
            v[2] = (short)f2bf(u0.z); v[3] = (short)f2bf(u0.w);
            v[4] = (short)f2bf(u1.x); v[5] = (short)f2bf(u1.y);
            v[6] = (short)f2bf(u1.z); v[7] = (short)f2bf(u1.w);
            *(bf16x8*)&xls[(r * 64 + (o ^ (r & 7))) * 8] = v;
        }
        __syncthreads();

        f32x4 acc0 = {0.f,0.f,0.f,0.f}, acc1 = {0.f,0.f,0.f,0.f};
        f32x4 acc2 = {0.f,0.f,0.f,0.f}, acc3 = {0.f,0.f,0.f,0.f};

        #pragma unroll 4
        for (int ks = 0; ks < 16; ++ks) {
            const int oct = ks * 4 + lg;
            const bf16x8 af = *(const bf16x8*)&xls[(ll * 64 + (oct ^ (ll & 7))) * 8];
            const ushort* cp = Cbf + (size_t)(w * 64 + ll) * FF + ks * 32 + lg * 8;
            const bf16x8 bf0 = *(const bf16x8*)(cp);
            const bf16x8 bf1 = *(const bf16x8*)(cp + 16 * FF);
            const bf16x8 bf2 = *(const bf16x8*)(cp + 32 * FF);
            const bf16x8 bf3 = *(const bf16x8*)(cp + 48 * FF);
            acc0 = __builtin_amdgcn_mfma_f32_16x16x32_bf16(af, bf0, acc0, 0, 0, 0);
            acc1 = __builtin_amdgcn_mfma_f32_16x16x32_bf16(af, bf1, acc1, 0, 0, 0);
            acc2 = __builtin_amdgcn_mfma_f32_16x16x32_bf16(af, bf2, acc2, 0, 0, 0);
            acc3 = __builtin_amdgcn_mfma_f32_16x16x32_bf16(af, bf3, acc3, 0, 0, 0);
        }

        // v[j][reg] = raw base + bias
        float v[4][4];
        #pragma unroll
        for (int r = 0; r < 4; ++r) {
            v[0][r] = acc0[r] + bias[0];
            v[1][r] = acc1[r] + bias[1];
            v[2][r] = acc2[r] + bias[2];
            v[3][r] = acc3[r] + bias[3];
        }

        // LN stats per row (row = lg*4+reg): j in-reg, ll via shuffle, w via LDS
        float S[4], Q[4];
        #pragma unroll
        for (int r = 0; r < 4; ++r) {
            S[r] = v[0][r] + v[1][r] + v[2][r] + v[3][r];
            Q[r] = v[0][r]*v[0][r] + v[1][r]*v[1][r] + v[2][r]*v[2][r] + v[3][r]*v[3][r];
        }
        #pragma unroll
        for (int off = 8; off >= 1; off >>= 1) {
            #pragma unroll
            for (int r = 0; r < 4; ++r) {
                S[r] += __shfl_xor(S[r], off);
                Q[r] += __shfl_xor(Q[r], off);
            }
        }
        if (ll == 0) {
            #pragma unroll
            for (int r = 0; r < 4; ++r) {
                redw[w][lg][r][0] = S[r];
                redw[w][lg][r][1] = Q[r];
            }
        }
        __syncthreads();

        const float wjc = wj[c];
        #pragma unroll
        for (int r = 0; r < 4; ++r) {
            float SS = 0.f, QQ = 0.f;
            #pragma unroll
            for (int q = 0; q < 8; ++q) {
                SS += redw[q][lg][r][0];
                QQ += redw[q][lg][r][1];
            }
            const float mu   = SS * (1.0f / DD);
            const float rstd = rsqrtf(QQ * (1.0f / DD) - mu * mu + LN_EPS);
            #pragma unroll
            for (int j = 0; j < 4; ++j)
                hacc[j][r] += wjc * ((v[j][r] - mu) * rstd * gam[j] + bet[j]);
        }
        __syncthreads();   // protect xls/redw for next c
    }

    // accumulate into out (order-independent up to fp add commutation; out zeroed by wm)
    #pragma unroll
    for (int r = 0; r < 4; ++r) {
        const int row = rh * 16 + lg * 4 + r;
        #pragma unroll
        for (int j = 0; j < 4; ++j)
            atomicAdd(out + (size_t)row * DD + w * 64 + j * 16 + ll, hacc[j][r]);
    }
}

extern "C" void kernel_launch(void* const* d_in, const int* in_sizes, int n_in,
                              void* d_out, int out_size, void* d_ws, size_t ws_size,
                              hipStream_t stream) {
    const float* x   = (const float*)d_in[0];
    const float* Pw  = (const float*)d_in[1];
    const float* Ww  = (const float*)d_in[2];
    const float* Wb  = (const float*)d_in[3];
    const float* bv  = (const float*)d_in[4];
    const float* lng = (const float*)d_in[5];
    const float* lnb = (const float*)d_in[6];
    // d_in[7] = alpha: unused — alpha*cal_scalar is d-constant; LayerNorm cancels it exactly.
    const float* th1 = (const float*)d_in[8];
    const float* ph1 = (const float*)d_in[9];
    const float* th2 = (const float*)d_in[10];
    const float* ph2 = (const float*)d_in[11];
    const float* w1  = (const float*)d_in[12];
    const float* w2  = (const float*)d_in[13];
    const float* bg  = (const float*)d_in[14];

    ushort* Cbf  = (ushort*)d_ws;                      // [D][F] bf16 = 512 KB
    float*  wj   = (float*)((char*)d_ws + (1 << 19));  // [512] weight table
    int*    nact = (int*)(wj + 512);                   // active-count

    weight_merge<<<256, 256, 0, stream>>>(Pw, Ww, Cbf, wj, nact, (float*)d_out,
                                          th1, ph1, th2, ph2, w1, w2, bg);

    dim3 bgrid(64, 2);
    base_ln<<<bgrid, 512, 0, stream>>>(x, Cbf, Wb, bv, lng, lnb, wj, nact,
                                       (float*)d_out);
}